// Round 9
// baseline (265.393 us; speedup 1.0000x reference)
//
#include <hip/hip_runtime.h>
#include <stdint.h>

#define N_NODES   50000
#define N_EDGES   800000
#define IN_DIM    128
#define OUT_DIM   128
#define NUM_RELS  8
#define THREADS   256

typedef _Float16 half_t;
typedef _Float16 half2v __attribute__((ext_vector_type(2)));
typedef _Float16 half4v __attribute__((ext_vector_type(4)));
typedef _Float16 half8 __attribute__((ext_vector_type(8)));
typedef float floatx4 __attribute__((ext_vector_type(4)));

// ============ plan ============
// 1. prep_wt (tiny) ; memset hist
// 2. FUSED: gemm (write/MFMA-bound) || hist (atomic-latency-bound) -- disjoint resources
// 3. scan_all (1 block, in-place hist -> exclusive prefix = cursors)
// 4. scatter: ONE u32 record/edge: src(16) | rel(3) | w13 (fixed-point)
// 5. wave per dst gather; beg/end from post-scatter cursors (inclusive prefix)

#define NBINS3    N_NODES                         // 50000

// ws layout (bytes) -- total 106,062,144 < 107,862,464 proven in R5-R8
#define WS_Y2     0                               // y2  : 50000 x 1024 f16 (102,400,000)
#define WS_WT     102400000                       // WT  : 1024 x 128 f16 (262,144)
#define WS_REC    102662144                       // rec : N_EDGES u32 (3,200,000)
#define WS_HIST   105862144                       // hist/cursors : 50000 i32 (200,000)
#define WS_NEED   (size_t)106062144

// ---- rel_emb [r][k][n] fp32 -> WT [r*128+n][k] f16
__global__ void prep_wt_kernel(const float* __restrict__ rel_emb, half_t* __restrict__ WT) {
    int t = blockIdx.x * blockDim.x + threadIdx.x;   // 512*256 = 131072 = 8*128*128
    int r = t >> 14, k = (t >> 7) & 127, n = t & 127;
    WT[(size_t)((r << 7) | n) * 128 + k] = (half_t)rel_emb[t];
}

// ---- single-block in-place exclusive scan over 50000 bins (R6-proven pattern)
__global__ __launch_bounds__(1024) void scan_all_kernel(int* __restrict__ hist) {
    __shared__ int sh[1024];
    const int t = threadIdx.x;
    int carry = 0;
    for (int c = 0; c < 13; c++) {                 // 13 * 4096 = 53248 >= 50000
        int i0 = c * 4096 + t * 4;
        int v0 = (i0     < NBINS3) ? hist[i0]     : 0;
        int v1 = (i0 + 1 < NBINS3) ? hist[i0 + 1] : 0;
        int v2 = (i0 + 2 < NBINS3) ? hist[i0 + 2] : 0;
        int v3 = (i0 + 3 < NBINS3) ? hist[i0 + 3] : 0;
        int s = v0 + v1 + v2 + v3;
        sh[t] = s; __syncthreads();
        for (int o = 1; o < 1024; o <<= 1) {
            int x = (t >= o) ? sh[t - o] : 0;
            __syncthreads();
            sh[t] += x;
            __syncthreads();
        }
        int run = carry + sh[t] - s;
        if (i0     < NBINS3) hist[i0]     = run; run += v0;
        if (i0 + 1 < NBINS3) hist[i0 + 1] = run; run += v1;
        if (i0 + 2 < NBINS3) hist[i0 + 2] = run; run += v2;
        if (i0 + 3 < NBINS3) hist[i0 + 3] = run;
        carry += sh[1023];
        __syncthreads();
    }
}

// ---- scatter: one packed u32 record per edge
__global__ void scatter_kernel(const int* __restrict__ dst, const int* __restrict__ src,
                               const int* __restrict__ rel, const float* __restrict__ ew,
                               int* __restrict__ cursors, unsigned* __restrict__ rec) {
    int i = blockIdx.x * blockDim.x + threadIdx.x;
    if (i < N_EDGES) {
        int pos = atomicAdd(&cursors[dst[i]], 1);
        unsigned w13 = (unsigned)(ew[i] * 8192.0f);          // w in [0,1) -> 0..8191
        rec[pos] = (w13 << 19) | ((unsigned)rel[i] << 16) | (unsigned)src[i];
    }
}

// ---- GEMM body (R7/R8-proven): y2[50000 x 1024] = f16(feat) @ WT^T
template<bool GUARD>
__device__ __forceinline__ void gemm_body(const float* __restrict__ feat,
                                          half_t* __restrict__ Ws,   // LDS
                                          half_t* __restrict__ y2,
                                          int m0, int n0, int wave, int lane) {
    const int q = lane >> 4, l16 = lane & 15;
    const int wm0 = m0 + wave * 32;

    float4 fr[2][4][2];
    #pragma unroll
    for (int ms = 0; ms < 2; ms++) {
        int node = wm0 + ms * 16 + l16;
        const float* fb = feat + (size_t)node * 128 + q * 8;
        bool ok = !GUARD || node < N_NODES;
        #pragma unroll
        for (int kk = 0; kk < 4; kk++)
            #pragma unroll
            for (int h = 0; h < 2; h++) {
                float4 v = {0.f, 0.f, 0.f, 0.f};
                if (ok) v = *(const float4*)(fb + kk * 32 + h * 4);
                fr[ms][kk][h] = v;
            }
    }
    __syncthreads();   // Ws staged

    half8 bf[2][4];
    #pragma unroll
    for (int ms = 0; ms < 2; ms++)
        #pragma unroll
        for (int kk = 0; kk < 4; kk++) {
            half8 hb;
            hb[0] = (half_t)fr[ms][kk][0].x; hb[1] = (half_t)fr[ms][kk][0].y;
            hb[2] = (half_t)fr[ms][kk][0].z; hb[3] = (half_t)fr[ms][kk][0].w;
            hb[4] = (half_t)fr[ms][kk][1].x; hb[5] = (half_t)fr[ms][kk][1].y;
            hb[6] = (half_t)fr[ms][kk][1].z; hb[7] = (half_t)fr[ms][kk][1].w;
            bf[ms][kk] = hb;
        }

    floatx4 acc[8][2];
    #pragma unroll
    for (int nt = 0; nt < 8; nt++)
        #pragma unroll
        for (int ms = 0; ms < 2; ms++) acc[nt][ms] = (floatx4){0.f, 0.f, 0.f, 0.f};

    #pragma unroll
    for (int kk = 0; kk < 4; kk++) {
        #pragma unroll
        for (int nt = 0; nt < 8; nt++) {
            int row = nt * 16 + l16;
            int phys = (kk * 4 + q) ^ (l16 & 7);
            half8 a = *(const half8*)(Ws + row * 128 + phys * 8);
            acc[nt][0] = __builtin_amdgcn_mfma_f32_16x16x32_f16(a, bf[0][kk], acc[nt][0], 0, 0, 0);
            acc[nt][1] = __builtin_amdgcn_mfma_f32_16x16x32_f16(a, bf[1][kk], acc[nt][1], 0, 0, 0);
        }
    }

    // epilogue: transpose through Ws, coalesced uint4 stores
    __syncthreads();
    #pragma unroll
    for (int nt = 0; nt < 8; nt++)
        #pragma unroll
        for (int ms = 0; ms < 2; ms++) {
            int nl = wave * 32 + ms * 16 + l16;
            int c  = nt * 4 + q;
            int p  = (c + nl) & 31;
            half4v hv;
            hv[0] = (half_t)acc[nt][ms][0]; hv[1] = (half_t)acc[nt][ms][1];
            hv[2] = (half_t)acc[nt][ms][2]; hv[3] = (half_t)acc[nt][ms][3];
            *(half4v*)(Ws + nl * 128 + p * 4) = hv;
        }
    #pragma unroll
    for (int i = 0; i < 8; i++) {
        int nl  = wave * 32 + i * 4 + (lane >> 4);
        int c16 = lane & 15;
        int p0 = (2 * c16 + nl) & 31;
        int p1 = (2 * c16 + 1 + nl) & 31;
        uint2 lo = *(const uint2*)(Ws + nl * 128 + p0 * 4);
        uint2 hi = *(const uint2*)(Ws + nl * 128 + p1 * 4);
        int node = m0 + nl;
        if (!GUARD || node < N_NODES) {
            uint4 v; v.x = lo.x; v.y = lo.y; v.z = hi.x; v.w = hi.y;
            *(uint4*)(y2 + (size_t)node * 1024 + n0 + c16 * 8) = v;
        }
    }
}

// ---- FUSED: gemm (3128 blocks) || hist (1568 blocks), period-3 interleave per XCD.
// xcd = bid&7, s = bid>>3 in [0,588): s%3<2 -> gemm (idx (s/3)*2+s%3, guard <391),
// s%3==2 -> hist (idx s/3, 0..195).
#define FUSEA_BLOCKS (8 * 588)
__global__ __launch_bounds__(THREADS) void fused_gh_kernel(
    const float* __restrict__ feat, const half_t* __restrict__ WT,
    half_t* __restrict__ y2, const int* __restrict__ dst, int* __restrict__ hist) {
    __shared__ half_t Ws[128 * 128];               // 32 KB (gemm role only)
    const int bid = blockIdx.x;
    const int xcd = bid & 7, s = bid >> 3;
    const int t = threadIdx.x;

    if (s % 3 != 2) {
        int gidx = (s / 3) * 2 + (s % 3);
        if (gidx >= 391) return;
        int work = xcd * 391 + gidx;               // XCD-contiguous m-chunks
        int mt = work >> 3, nt8 = work & 7;
        const int m0 = mt * 128, n0 = nt8 * 128;
        const int wave = t >> 6, lane = t & 63;

        for (int i = t; i < 2048; i += THREADS) {
            int row = i >> 4, lc = i & 15;
            int phys = lc ^ (row & 7);
            *(uint4*)&Ws[row * 128 + phys * 8] =
                *(const uint4*)(WT + (size_t)(n0 + row) * 128 + lc * 8);
        }
        if (m0 + 128 <= N_NODES)
            gemm_body<false>(feat, Ws, y2, m0, n0, wave, lane);
        else
            gemm_body<true>(feat, Ws, y2, m0, n0, wave, lane);
    } else {
        int hb = xcd * 196 + s / 3;                // 0..1567
        int i = hb * 512 + t;
        int d0 = (i < N_EDGES) ? dst[i] : -1;
        int d1 = (i + 256 < N_EDGES) ? dst[i + 256] : -1;
        if (d0 >= 0) atomicAdd(&hist[d0], 1);
        if (d1 >= 0) atomicAdd(&hist[d1], 1);
    }
}

// ---- wave per dst, unroll-8; bounds from post-scatter cursors (inclusive prefix)
__global__ __launch_bounds__(THREADS) void gather_kernel(
    const half_t* __restrict__ y2, const unsigned* __restrict__ rec,
    const int* __restrict__ cur, float* __restrict__ out) {
    int g = blockIdx.x * 4 + (threadIdx.x >> 6);
    int lane = threadIdx.x & 63;
    int beg = (g > 0) ? cur[g - 1] : 0;
    int end = cur[g];
    const half_t* yb = y2 + lane * 2;
    float ax = 0.f, ay = 0.f, cx = 0.f, cy = 0.f;
    int e = beg;
    for (; e + 8 <= end; e += 8) {
        unsigned r0 = rec[e],     r1 = rec[e + 1], r2 = rec[e + 2], r3 = rec[e + 3];
        unsigned r4 = rec[e + 4], r5 = rec[e + 5], r6 = rec[e + 6], r7 = rec[e + 7];
        int b0 = (int)((r0 & 0xFFFFu) << 10) | (int)(((r0 >> 16) & 7u) << 7);
        int b1 = (int)((r1 & 0xFFFFu) << 10) | (int)(((r1 >> 16) & 7u) << 7);
        int b2 = (int)((r2 & 0xFFFFu) << 10) | (int)(((r2 >> 16) & 7u) << 7);
        int b3 = (int)((r3 & 0xFFFFu) << 10) | (int)(((r3 >> 16) & 7u) << 7);
        int b4 = (int)((r4 & 0xFFFFu) << 10) | (int)(((r4 >> 16) & 7u) << 7);
        int b5 = (int)((r5 & 0xFFFFu) << 10) | (int)(((r5 >> 16) & 7u) << 7);
        int b6 = (int)((r6 & 0xFFFFu) << 10) | (int)(((r6 >> 16) & 7u) << 7);
        int b7 = (int)((r7 & 0xFFFFu) << 10) | (int)(((r7 >> 16) & 7u) << 7);
        half2v v0 = *(const half2v*)(yb + b0);
        half2v v1 = *(const half2v*)(yb + b1);
        half2v v2 = *(const half2v*)(yb + b2);
        half2v v3 = *(const half2v*)(yb + b3);
        half2v v4 = *(const half2v*)(yb + b4);
        half2v v5 = *(const half2v*)(yb + b5);
        half2v v6 = *(const half2v*)(yb + b6);
        half2v v7 = *(const half2v*)(yb + b7);
        const float ws = 1.0f / 8192.0f;
        float w0 = (float)(r0 >> 19) * ws, w1 = (float)(r1 >> 19) * ws;
        float w2 = (float)(r2 >> 19) * ws, w3 = (float)(r3 >> 19) * ws;
        float w4 = (float)(r4 >> 19) * ws, w5 = (float)(r5 >> 19) * ws;
        float w6 = (float)(r6 >> 19) * ws, w7 = (float)(r7 >> 19) * ws;
        ax += w0 * (float)v0[0] + w1 * (float)v1[0];
        ay += w0 * (float)v0[1] + w1 * (float)v1[1];
        cx += w2 * (float)v2[0] + w3 * (float)v3[0];
        cy += w2 * (float)v2[1] + w3 * (float)v3[1];
        ax += w4 * (float)v4[0] + w5 * (float)v5[0];
        ay += w4 * (float)v4[1] + w5 * (float)v5[1];
        cx += w6 * (float)v6[0] + w7 * (float)v7[0];
        cy += w6 * (float)v6[1] + w7 * (float)v7[1];
    }
    for (; e < end; e++) {
        unsigned r = rec[e];
        int b = (int)((r & 0xFFFFu) << 10) | (int)(((r >> 16) & 7u) << 7);
        float w = (float)(r >> 19) * (1.0f / 8192.0f);
        half2v v = *(const half2v*)(yb + b);
        ax += w * (float)v[0];
        ay += w * (float)v[1];
    }
    float2 o; o.x = ax + cx; o.y = ay + cy;
    *(float2*)(out + (size_t)g * 128 + lane * 2) = o;
}

// ---- fallback (tiny ws): wave-per-edge direct with atomics
__global__ void naive_kernel(const float* __restrict__ feat, const float* __restrict__ rel_emb,
                             const float* __restrict__ ew, const int* __restrict__ src,
                             const int* __restrict__ dst, const int* __restrict__ rel,
                             float* __restrict__ out) {
    int wave = (blockIdx.x * blockDim.x + threadIdx.x) >> 6;
    int lane = threadIdx.x & 63;
    if (wave >= N_EDGES) return;
    const float* f = feat + (size_t)src[wave] * IN_DIM;
    const float* W = rel_emb + (size_t)rel[wave] * IN_DIM * OUT_DIM;
    float w = ew[wave];
    float a0 = 0.f, a1 = 0.f;
    for (int k = 0; k < IN_DIM; k++) {
        float fv = f[k];
        a0 += fv * W[k * OUT_DIM + lane];
        a1 += fv * W[k * OUT_DIM + 64 + lane];
    }
    int d = dst[wave];
    atomicAdd(&out[(size_t)d * OUT_DIM + lane], a0 * w);
    atomicAdd(&out[(size_t)d * OUT_DIM + 64 + lane], a1 * w);
}

extern "C" void kernel_launch(void* const* d_in, const int* in_sizes, int n_in,
                              void* d_out, int out_size, void* d_ws, size_t ws_size,
                              hipStream_t stream) {
    const float* feat    = (const float*)d_in[0];
    const float* rel_emb = (const float*)d_in[1];
    const float* ew      = (const float*)d_in[2];
    const int*   src     = (const int*)d_in[3];
    const int*   dst     = (const int*)d_in[4];
    const int*   rel     = (const int*)d_in[5];
    float* out = (float*)d_out;

    const int eb = (N_EDGES + THREADS - 1) / THREADS;   // 3125

    if (ws_size >= WS_NEED) {
        char* ws = (char*)d_ws;
        half_t*   y2   = (half_t*)(ws + WS_Y2);
        half_t*   WT   = (half_t*)(ws + WS_WT);
        unsigned* rec  = (unsigned*)(ws + WS_REC);
        int*      hist = (int*)(ws + WS_HIST);

        hipMemsetAsync(hist, 0, (size_t)NBINS3 * 4, stream);
        prep_wt_kernel<<<512, THREADS, 0, stream>>>(rel_emb, WT);
        fused_gh_kernel<<<FUSEA_BLOCKS, THREADS, 0, stream>>>(feat, WT, y2, dst, hist);
        scan_all_kernel<<<1, 1024, 0, stream>>>(hist);           // hist -> exclusive prefix
        scatter_kernel<<<eb, THREADS, 0, stream>>>(dst, src, rel, ew, hist, rec);
        gather_kernel<<<N_NODES / 4, THREADS, 0, stream>>>(y2, rec, hist, out);
    } else {
        hipMemsetAsync(d_out, 0, (size_t)out_size * sizeof(float), stream);
        const long long total = (long long)N_EDGES * 64;
        const int blocks = (int)((total + THREADS - 1) / THREADS);
        naive_kernel<<<blocks, THREADS, 0, stream>>>(feat, rel_emb, ew, src, dst, rel, out);
    }
}